// Round 7
// baseline (2273.732 us; speedup 1.0000x reference)
//
#include <hip/hip_runtime.h>

#define NN 12288
#define OUTF 64
#define ALPHA 0.2f
#define C1 6.0f

typedef unsigned short u16;
typedef unsigned int u32;
typedef unsigned long long u64;
typedef _Float16 half8 __attribute__((ext_vector_type(8)));
typedef float floatx4 __attribute__((ext_vector_type(4)));

union H16 { u16 u; _Float16 h; };
__device__ __forceinline__ u16 f2h(float f) { H16 c; c.h = (_Float16)f; return c.u; }

// ---------------- K1: h = X@W, per-node scalars, Btf in MFMA-fragment order --------------
// Btf chunk (k32, n): 64 lanes x 16 B contiguous; lane element j' = B_row(n*16+lane%16),
// source node k32*32 + (lane/16)*8 + j'.  B_row r: r<64: e1*h[r]; r==64: e1; 65..79: 0;
// 80..143: e2*h[r-80]; r==144: e2; 145..159: 0.   e1=exp(s2-C1), e2=exp(a*s2).
__global__ __launch_bounds__(256) void k1_prep(
    const float* __restrict__ inp, const float* __restrict__ W, const float* __restrict__ a,
    u16* __restrict__ e1h, u16* __restrict__ thh,
    float* __restrict__ f1g, float* __restrict__ f2g, u16* __restrict__ Btf)
{
  __shared__ float Wl[128 * 64];
  __shared__ float hsm[16][66];
  __shared__ float e1sm[16], e2sm[16];
  const int tid = threadIdx.x;
  for (int t = tid; t < 128 * 64 / 4; t += 256)
    ((float4*)Wl)[t] = ((const float4*)W)[t];
  const int wave = tid >> 6, lane = tid & 63;
  const int k16 = blockIdx.x;                  // 16-node group
  const float a1l = a[lane], a2l = a[OUTF + lane];
  __syncthreads();
  for (int jl = 0; jl < 4; ++jl) {
    const int jn = wave * 4 + jl;              // local node 0..15
    const int j = k16 * 16 + jn;
    const float4* xp = (const float4*)(inp + (size_t)j * 128);
    float h = 0.f;
#pragma unroll
    for (int c4 = 0; c4 < 32; ++c4) {
      float4 v = xp[c4];
      const int k = c4 * 4;
      h += v.x * Wl[k * 64 + lane] + v.y * Wl[(k + 1) * 64 + lane]
         + v.z * Wl[(k + 2) * 64 + lane] + v.w * Wl[(k + 3) * 64 + lane];
    }
    float p1 = h * a1l, p2 = h * a2l;
#pragma unroll
    for (int off = 32; off > 0; off >>= 1) { p1 += __shfl_xor(p1, off); p2 += __shfl_xor(p2, off); }
    hsm[jn][lane] = h;
    if (lane == 0) {
      const float s1 = p1, s2 = p2;
      const float e1 = expf(s2 - C1), e2 = expf(ALPHA * s2);
      e1sm[jn] = e1; e2sm[jn] = e2;
      e1h[j] = f2h(e1);
      thh[j] = f2h(expf(-s1 - C1));            // pos branch iff e1h[j] > thh[i] (u16-monotone)
      f1g[j] = expf(s1 + C1);
      f2g[j] = expf(ALPHA * s1);
    }
  }
  __syncthreads();
  // phase B: this block covers half a k32 slab: lanes [hi, hi+32) of every n-chunk
  const int k32 = k16 >> 1, hi = (k16 & 1) * 32;
  for (int cc = tid; cc < 320; cc += 256) {
    const int n = cc >> 5, l32 = cc & 31;
    const int r = n * 16 + (l32 & 15);
    const int jb = (l32 >> 4) * 8;             // local node base for this lane's 8 elements
    u32 wpk[4];
#pragma unroll
    for (int p = 0; p < 4; ++p) {
      u16 hh[2];
#pragma unroll
      for (int q2 = 0; q2 < 2; ++q2) {
        const int jj = jb + p * 2 + q2;
        float v;
        if (r < 64)        v = e1sm[jj] * hsm[jj][r];
        else if (r == 64)  v = e1sm[jj];
        else if (r < 80)   v = 0.f;
        else if (r < 144)  v = e2sm[jj] * hsm[jj][r - 80];
        else if (r == 144) v = e2sm[jj];
        else               v = 0.f;
        hh[q2] = f2h(v);
      }
      wpk[p] = (u32)hh[0] | ((u32)hh[1] << 16);
    }
    ((uint4*)Btf)[(size_t)(k32 * 10 + n) * 64 + hi + l32] = make_uint4(wpk[0], wpk[1], wpk[2], wpk[3]);
  }
}

// ---------------- K_PACK: ballot-based mask build, one row per wave ----------------------
// P1[i] word w, bit l  =  adj[i][w*64+l]>0 && e1h[w*64+l] > thh[i];  P2 = adj && !up.
// Wave loads 64 contiguous adj ints per step (256 B coalesced), ballots, and stores the
// accumulated 64 words as one 512-B burst per batch.
__global__ __launch_bounds__(256) void k_pack(
    const int* __restrict__ adj, const u16* __restrict__ e1h, const u16* __restrict__ thh,
    u64* __restrict__ P1, u64* __restrict__ P2)
{
  const int wave = threadIdx.x >> 6, lane = threadIdx.x & 63;
  const int i = blockIdx.x * 4 + wave;
  const u32 th = thh[i];
  const int* arow = adj + (size_t)i * NN;
  u64* p1r = P1 + (size_t)i * (NN / 64);
  u64* p2r = P2 + (size_t)i * (NN / 64);
#pragma unroll
  for (int b = 0; b < 3; ++b) {
    u64 st1 = 0, st2 = 0;
    for (int s = 0; s < 64; ++s) {
      const int col = (b * 64 + s) * 64 + lane;
      const int av = arow[col];
      const u32 ev = e1h[col];
      const u64 madj = __ballot(av > 0);
      const u64 mup = __ballot(ev > th);       // positive fp16 compares as u16
      if (lane == s) { st1 = madj & mup; st2 = madj & ~mup; }
    }
    p1r[b * 64 + lane] = st1;
    p2r[b * 64 + lane] = st2;
  }
}

// ---------------- K2: bit-masked dual GEMM; waves split M, share B via L1 ----------------
// 192 blocks x 256; block b rows [b*64, b*64+64); wave w rows [w*16,w*16+16), FULL K.
// Barrier per k64 keeps the 4 waves on the same B chunk (one L1 fill serves all).
// Full-K per wave -> complete sums in-wave: no reduction anywhere.
__global__ __launch_bounds__(256) void k2_main(
    const u64* __restrict__ P1, const u64* __restrict__ P2,
    const u16* __restrict__ Btf, const float* __restrict__ f1g, const float* __restrict__ f2g,
    float* __restrict__ out)
{
  const int tid = threadIdx.x;
  const int wave = tid >> 6, lane = tid & 63;
  const int quad = lane >> 4, lr = lane & 15;
  const int wbase = (int)blockIdx.x * 64 + wave * 16;
  const int ia = wbase + lr;                   // A-operand row for this lane
  const u64* b1row = P1 + (size_t)ia * (NN / 64);
  const u64* b2row = P2 + (size_t)ia * (NN / 64);

  floatx4 acc[10];
#pragma unroll
  for (int n = 0; n < 10; ++n) acc[n] = (floatx4){0.f, 0.f, 0.f, 0.f};

  for (int kb = 0; kb < NN; kb += 64) {
    __syncthreads();                           // keep waves converged for L1 B-reuse
    const u64 b1 = b1row[kb >> 6];
    const u64 b2 = b2row[kb >> 6];
#pragma unroll
    for (int h = 0; h < 2; ++h) {
      const int k32 = (kb >> 5) + h;
      const u32 sh = (u32)(h * 32 + quad * 8);
      const u32 m1 = (u32)(b1 >> sh) & 0xFFu;
      const u32 m2 = (u32)(b2 >> sh) & 0xFFu;
      union { half8 v; u16 s[8]; } A1, A2;
#pragma unroll
      for (int e = 0; e < 8; ++e) {
        A1.s[e] = ((m1 >> e) & 1u) ? (u16)0x3C00 : (u16)0;
        A2.s[e] = ((m2 >> e) & 1u) ? (u16)0x3C00 : (u16)0;
      }
      const half8* bp = reinterpret_cast<const half8*>(Btf + ((size_t)k32 * 10 * 64 + lane) * 8);
#pragma unroll
      for (int n = 0; n < 10; ++n) {
        half8 Bv = bp[n * 64];                 // same addr in all 4 waves -> L1 broadcast
        acc[n] = __builtin_amdgcn_mfma_f32_16x16x32_f16(n < 5 ? A1.v : A2.v, Bv, acc[n], 0, 0, 0);
      }
    }
  }

  // Epilogue, fully in-wave. C/D: col=lane&15, row=quad*4+reg.
  // den+ = acc[4][r] at col 0 (lane quad*16); den- = acc[9][r] at col 0.
#pragma unroll
  for (int r = 0; r < 4; ++r) {
    const int row = wbase + quad * 4 + r;
    const float f1 = f1g[row], f2 = f2g[row];
    const float d1 = __shfl(acc[4][r], quad << 4);
    const float d2 = __shfl(acc[9][r], quad << 4);
    const float den = fmaxf(f1 * d1 + f2 * d2, 1e-30f);
#pragma unroll
    for (int g = 0; g < 4; ++g) {
      const float num = f1 * acc[g][r] + f2 * acc[5 + g][r];
      const float x = num / den;
      out[(size_t)row * OUTF + g * 16 + lr] = x > 0.f ? x : (expf(x) - 1.f);
    }
  }
}

extern "C" void kernel_launch(void* const* d_in, const int* in_sizes, int n_in,
                              void* d_out, int out_size, void* d_ws, size_t ws_size,
                              hipStream_t stream) {
  const float* inp = (const float*)d_in[0];
  const int* adj = (const int*)d_in[1];
  const float* W = (const float*)d_in[2];
  const float* a = (const float*)d_in[3];

  // ws: Btf 3,932,160 | P1 18,874,368 | P2 18,874,368 | e1h 24,576 | thh 24,576
  //     f1g 49,152 | f2g 49,152   (total ~41.8 MB)
  char* ws = (char*)d_ws;
  u16* Btf = (u16*)ws;
  u64* P1 = (u64*)(ws + 3932160);
  u64* P2 = (u64*)(ws + 3932160 + 18874368);
  u16* e1h = (u16*)(ws + 3932160 + 2 * 18874368);
  u16* thh = e1h + NN;
  float* f1g = (float*)(thh + NN);
  float* f2g = f1g + NN;

  k1_prep<<<768, 256, 0, stream>>>(inp, W, a, e1h, thh, f1g, f2g, Btf);
  k_pack<<<NN / 4, 256, 0, stream>>>(adj, e1h, thh, P1, P2);
  k2_main<<<192, 256, 0, stream>>>(P1, P2, Btf, f1g, f2g, (float*)d_out);
}

// Round 8
// 1043.894 us; speedup vs baseline: 2.1781x; 2.1781x over previous
//
#include <hip/hip_runtime.h>

#define NN 12288
#define OUTF 64
#define ALPHA 0.2f
#define C1 6.0f

typedef unsigned short u16;
typedef unsigned int u32;
typedef unsigned long long u64;
typedef _Float16 half8 __attribute__((ext_vector_type(8)));
typedef float floatx4 __attribute__((ext_vector_type(4)));
typedef int intx4 __attribute__((ext_vector_type(4)));

union H16 { u16 u; _Float16 h; };
__device__ __forceinline__ u16 f2h(float f) { H16 c; c.h = (_Float16)f; return c.u; }

// ---------------- K1: h = X@W, per-node scalars, Btf in MFMA-fragment order --------------
// Btf chunk (k32, n): 64 lanes x 16 B contiguous; lane element j' = B_row(n*16+lane%16),
// source node k32*32 + (lane/16)*8 + j'.  B_row r: r<64: e1*h[r]; r==64: e1; 65..79: 0;
// 80..143: e2*h[r-80]; r==144: e2; 145..159: 0.   e1=exp(s2-C1), e2=exp(a*s2).
__global__ __launch_bounds__(256) void k1_prep(
    const float* __restrict__ inp, const float* __restrict__ W, const float* __restrict__ a,
    u16* __restrict__ e1h, u16* __restrict__ thh,
    float* __restrict__ f1g, float* __restrict__ f2g, u16* __restrict__ Btf)
{
  __shared__ float Wl[128 * 64];
  __shared__ float hsm[16][66];
  __shared__ float e1sm[16], e2sm[16];
  const int tid = threadIdx.x;
  for (int t = tid; t < 128 * 64 / 4; t += 256)
    ((float4*)Wl)[t] = ((const float4*)W)[t];
  const int wave = tid >> 6, lane = tid & 63;
  const int k16 = blockIdx.x;                  // 16-node group
  const float a1l = a[lane], a2l = a[OUTF + lane];
  __syncthreads();
  for (int jl = 0; jl < 4; ++jl) {
    const int jn = wave * 4 + jl;              // local node 0..15
    const int j = k16 * 16 + jn;
    const float4* xp = (const float4*)(inp + (size_t)j * 128);
    float h = 0.f;
#pragma unroll
    for (int c4 = 0; c4 < 32; ++c4) {
      float4 v = xp[c4];
      const int k = c4 * 4;
      h += v.x * Wl[k * 64 + lane] + v.y * Wl[(k + 1) * 64 + lane]
         + v.z * Wl[(k + 2) * 64 + lane] + v.w * Wl[(k + 3) * 64 + lane];
    }
    float p1 = h * a1l, p2 = h * a2l;
#pragma unroll
    for (int off = 32; off > 0; off >>= 1) { p1 += __shfl_xor(p1, off); p2 += __shfl_xor(p2, off); }
    hsm[jn][lane] = h;
    if (lane == 0) {
      const float s1 = p1, s2 = p2;
      const float e1 = expf(s2 - C1), e2 = expf(ALPHA * s2);
      e1sm[jn] = e1; e2sm[jn] = e2;
      e1h[j] = f2h(e1);
      thh[j] = f2h(expf(-s1 - C1));            // pos branch iff e1h[j] > thh[i] (u16-monotone)
      f1g[j] = expf(s1 + C1);
      f2g[j] = expf(ALPHA * s1);
    }
  }
  __syncthreads();
  // phase B: this block covers half a k32 slab: lanes [hi, hi+32) of every n-chunk
  const int k32 = k16 >> 1, hi = (k16 & 1) * 32;
  for (int cc = tid; cc < 320; cc += 256) {
    const int n = cc >> 5, l32 = cc & 31;
    const int r = n * 16 + (l32 & 15);
    const int jb = (l32 >> 4) * 8;             // local node base for this lane's 8 elements
    u32 wpk[4];
#pragma unroll
    for (int p = 0; p < 4; ++p) {
      u16 hh[2];
#pragma unroll
      for (int q2 = 0; q2 < 2; ++q2) {
        const int jj = jb + p * 2 + q2;
        float v;
        if (r < 64)        v = e1sm[jj] * hsm[jj][r];
        else if (r == 64)  v = e1sm[jj];
        else if (r < 80)   v = 0.f;
        else if (r < 144)  v = e2sm[jj] * hsm[jj][r - 80];
        else if (r == 144) v = e2sm[jj];
        else               v = 0.f;
        hh[q2] = f2h(v);
      }
      wpk[p] = (u32)hh[0] | ((u32)hh[1] << 16);
    }
    ((uint4*)Btf)[(size_t)(k32 * 10 + n) * 64 + hi + l32] = make_uint4(wpk[0], wpk[1], wpk[2], wpk[3]);
  }
}

// ---------------- K_PACK (R5-proven byte version): adj -> branch-resolved bit masks ------
// P1 bit j of row i = adj[i][j]!=0 && e1h[j] > thh[i];  P2 = adj && !up.  1 block per row.
// Byte k of a row covers cols [8k, 8k+8) -> little-endian-compatible with u64 reads.
__global__ __launch_bounds__(256) void k_pack(
    const int* __restrict__ adj, const u16* __restrict__ e1h, const u16* __restrict__ thh,
    unsigned char* __restrict__ P1, unsigned char* __restrict__ P2)
{
  const int i = blockIdx.x, tid = threadIdx.x;
  const u16 th = thh[i];
  const int* arow = adj + (size_t)i * NN;
  unsigned char* p1r = P1 + (size_t)i * (NN / 8);
  unsigned char* p2r = P2 + (size_t)i * (NN / 8);
#pragma unroll
  for (int it = 0; it < NN / 2048; ++it) {
    const int cb = it * 2048 + tid * 8;
    intx4 a0 = *reinterpret_cast<const intx4*>(arow + cb);
    intx4 a1 = *reinterpret_cast<const intx4*>(arow + cb + 4);
    uint4 ev = *reinterpret_cast<const uint4*>(e1h + cb);
    const int av[8] = {a0.x, a0.y, a0.z, a0.w, a1.x, a1.y, a1.z, a1.w};
    const u32 ew[4] = {ev.x, ev.y, ev.z, ev.w};
    u32 b1 = 0, b2 = 0;
#pragma unroll
    for (int e = 0; e < 8; ++e) {
      const u16 eh = (u16)(ew[e >> 1] >> ((e & 1) * 16));
      const bool bit = av[e] != 0;
      const bool up = eh > th;                 // positive fp16 compares as u16
      b1 |= (u32)(bit && up) << e;
      b2 |= (u32)(bit && !up) << e;
    }
    p1r[it * 256 + tid] = (unsigned char)b1;
    p2r[it * 256 + tid] = (unsigned char)b2;
  }
}

// ---------------- K2: bit-masked dual GEMM, M=32/wave (2 tiles), R5 scheduling -----------
// 768 blocks = 384 m-positions x 2 k-halves; 4 waves split the k-half (1536 each).
// No barriers in the K-loop; 12 waves/CU hide L2 latency; ~92K lines/CU total.
__global__ __launch_bounds__(256, 3) void k2_main(
    const u64* __restrict__ P1, const u64* __restrict__ P2,
    const u16* __restrict__ Btf, float* __restrict__ part)
{
  __shared__ float red[32][132];               // 16.9 KB: cols 0-63 pos, 64-127 neg, 128/129 dens
  const int tid = threadIdx.x;
  const int wave = tid >> 6, lane = tid & 63;
  const int quad = lane >> 4, lr = lane & 15;
  const int mpos = (int)blockIdx.x >> 1;
  const int khalf = (int)blockIdx.x & 1;
  const int mbase = mpos * 32;

  for (int i = tid; i < 32 * 132; i += 256) (&red[0][0])[i] = 0.f;

  const u64* b1p[2] = {P1 + (size_t)(mbase + lr) * (NN / 64),
                       P1 + (size_t)(mbase + 16 + lr) * (NN / 64)};
  const u64* b2p[2] = {P2 + (size_t)(mbase + lr) * (NN / 64),
                       P2 + (size_t)(mbase + 16 + lr) * (NN / 64)};
  const int k0 = khalf * (NN / 2) + wave * (NN / 8);

  floatx4 acc[2][10];
#pragma unroll
  for (int t = 0; t < 2; ++t)
#pragma unroll
    for (int n = 0; n < 10; ++n) acc[t][n] = (floatx4){0.f, 0.f, 0.f, 0.f};

  __syncthreads();

  for (int kb = k0; kb < k0 + NN / 8; kb += 64) {
    const u64 b1a = b1p[0][kb >> 6], b1b = b1p[1][kb >> 6];
    const u64 b2a = b2p[0][kb >> 6], b2b = b2p[1][kb >> 6];
#pragma unroll
    for (int h = 0; h < 2; ++h) {
      const int k32 = (kb >> 5) + h;
      const u32 sh = (u32)(h * 32 + quad * 8);
      union { half8 v; u16 s[8]; } A1[2], A2[2];
      const u32 m1a = (u32)(b1a >> sh) & 0xFFu, m2a = (u32)(b2a >> sh) & 0xFFu;
      const u32 m1b = (u32)(b1b >> sh) & 0xFFu, m2b = (u32)(b2b >> sh) & 0xFFu;
#pragma unroll
      for (int e = 0; e < 8; ++e) {
        A1[0].s[e] = ((m1a >> e) & 1u) ? (u16)0x3C00 : (u16)0;
        A2[0].s[e] = ((m2a >> e) & 1u) ? (u16)0x3C00 : (u16)0;
        A1[1].s[e] = ((m1b >> e) & 1u) ? (u16)0x3C00 : (u16)0;
        A2[1].s[e] = ((m2b >> e) & 1u) ? (u16)0x3C00 : (u16)0;
      }
      const half8* bp = reinterpret_cast<const half8*>(Btf + ((size_t)k32 * 10 * 64 + lane) * 8);
#pragma unroll
      for (int n = 0; n < 10; ++n) {
        half8 Bv = bp[n * 64];                 // one 1-KB coalesced load feeds both m-tiles
        acc[0][n] = __builtin_amdgcn_mfma_f32_16x16x32_f16(n < 5 ? A1[0].v : A2[0].v, Bv,
                                                           acc[0][n], 0, 0, 0);
        acc[1][n] = __builtin_amdgcn_mfma_f32_16x16x32_f16(n < 5 ? A1[1].v : A2[1].v, Bv,
                                                           acc[1][n], 0, 0, 0);
      }
    }
  }

  // C/D: col=lane&15, row=quad*4+reg; tile t -> local rows t*16..t*16+15
#pragma unroll
  for (int t = 0; t < 2; ++t) {
#pragma unroll
    for (int n = 0; n < 4; ++n)
#pragma unroll
      for (int r = 0; r < 4; ++r)
        atomicAdd(&red[t * 16 + quad * 4 + r][n * 16 + lr], acc[t][n][r]);
#pragma unroll
    for (int n = 5; n < 9; ++n)
#pragma unroll
      for (int r = 0; r < 4; ++r)
        atomicAdd(&red[t * 16 + quad * 4 + r][64 + (n - 5) * 16 + lr], acc[t][n][r]);
    if (lr == 0) {
#pragma unroll
      for (int r = 0; r < 4; ++r) {
        atomicAdd(&red[t * 16 + quad * 4 + r][128], acc[t][4][r]);  // den+ (chunk 4, col 0)
        atomicAdd(&red[t * 16 + quad * 4 + r][129], acc[t][9][r]);  // den- (chunk 9, col 0)
      }
    }
  }
  __syncthreads();

  float* pp = part + ((size_t)khalf * 384 + mpos) * (32 * 132);
  for (int i = tid; i < 32 * 132; i += 256) pp[i] = (&red[0][0])[i];
}

// ---------------- K3: combine the 2 k-half partials, scale, divide, ELU ------------------
__global__ __launch_bounds__(256) void k3_final(
    const float* __restrict__ part, const float* __restrict__ f1g,
    const float* __restrict__ f2g, float* __restrict__ out)
{
  const int gid = blockIdx.x * 256 + threadIdx.x;
  const int row = gid >> 6, col = gid & 63;
  const int mpos = row >> 5, r = row & 31;
  const float* pa = part + ((size_t)mpos) * (32 * 132) + r * 132;
  const float* pb = part + ((size_t)(384 + mpos)) * (32 * 132) + r * 132;
  const float n1 = pa[col] + pb[col];
  const float n2 = pa[64 + col] + pb[64 + col];
  const float d1 = pa[128] + pb[128];
  const float d2 = pa[129] + pb[129];
  const float f1 = f1g[row], f2 = f2g[row];
  const float num = f1 * n1 + f2 * n2;
  const float den = fmaxf(f1 * d1 + f2 * d2, 1e-30f);
  const float x = num / den;
  out[gid] = x > 0.f ? x : (expf(x) - 1.f);
}

extern "C" void kernel_launch(void* const* d_in, const int* in_sizes, int n_in,
                              void* d_out, int out_size, void* d_ws, size_t ws_size,
                              hipStream_t stream) {
  const float* inp = (const float*)d_in[0];
  const int* adj = (const int*)d_in[1];
  const float* W = (const float*)d_in[2];
  const float* a = (const float*)d_in[3];

  // ws: Btf 3,932,160 | P1 18,874,368 | P2 18,874,368 | part 12,976,128
  //     e1h 24,576 | thh 24,576 | f1g 49,152 | f2g 49,152   (total ~54.8 MB)
  char* ws = (char*)d_ws;
  u16* Btf = (u16*)ws;
  unsigned char* P1 = (unsigned char*)(ws + 3932160);
  unsigned char* P2 = P1 + 18874368;
  float* part = (float*)(ws + 3932160 + 2 * 18874368);
  char* tail = ws + 3932160 + 2 * 18874368 + 12976128;
  u16* e1h = (u16*)tail;
  u16* thh = e1h + NN;
  float* f1g = (float*)(thh + NN);
  float* f2g = f1g + NN;

  k1_prep<<<768, 256, 0, stream>>>(inp, W, a, e1h, thh, f1g, f2g, Btf);
  k_pack<<<NN, 256, 0, stream>>>(adj, e1h, thh, P1, P2);
  k2_main<<<768, 256, 0, stream>>>((const u64*)P1, (const u64*)P2, Btf, part);
  k3_final<<<NN * OUTF / 256, 256, 0, stream>>>(part, f1g, f2g, (float*)d_out);
}

// Round 9
// 898.829 us; speedup vs baseline: 2.5297x; 1.1614x over previous
//
#include <hip/hip_runtime.h>

#define NN 12288
#define OUTF 64
#define ALPHA 0.2f
#define C1 6.0f
#define KSP 8
#define KRANGE (NN / KSP)    /* 1536 per block */
#define ITERS (KRANGE / 64)  /* 24 */

typedef unsigned short u16;
typedef unsigned int u32;
typedef unsigned long long u64;
typedef _Float16 half8 __attribute__((ext_vector_type(8)));
typedef float floatx4 __attribute__((ext_vector_type(4)));
typedef int intx4 __attribute__((ext_vector_type(4)));

union H16 { u16 u; _Float16 h; };
__device__ __forceinline__ u16 f2h(float f) { H16 c; c.h = (_Float16)f; return c.u; }

// ---------------- K1: h = X@W, per-node scalars, Btf in MFMA-fragment order --------------
// Btf chunk (k32, n): 64 lanes x 16 B contiguous; lane element j' = B_row(n*16+lane%16),
// source node k32*32 + (lane/16)*8 + j'.  B_row r: r<64: e1*h[r]; r==64: e1; 65..79: 0;
// 80..143: e2*h[r-80]; r==144: e2; 145..159: 0.   e1=exp(s2-C1), e2=exp(a*s2).
__global__ __launch_bounds__(256) void k1_prep(
    const float* __restrict__ inp, const float* __restrict__ W, const float* __restrict__ a,
    u16* __restrict__ e1h, u16* __restrict__ thh,
    float* __restrict__ f1g, float* __restrict__ f2g, u16* __restrict__ Btf)
{
  __shared__ float Wl[128 * 64];
  __shared__ float hsm[16][66];
  __shared__ float e1sm[16], e2sm[16];
  const int tid = threadIdx.x;
  for (int t = tid; t < 128 * 64 / 4; t += 256)
    ((float4*)Wl)[t] = ((const float4*)W)[t];
  const int wave = tid >> 6, lane = tid & 63;
  const int k16 = blockIdx.x;                  // 16-node group
  const float a1l = a[lane], a2l = a[OUTF + lane];
  __syncthreads();
  for (int jl = 0; jl < 4; ++jl) {
    const int jn = wave * 4 + jl;              // local node 0..15
    const int j = k16 * 16 + jn;
    const float4* xp = (const float4*)(inp + (size_t)j * 128);
    float h = 0.f;
#pragma unroll
    for (int c4 = 0; c4 < 32; ++c4) {
      float4 v = xp[c4];
      const int k = c4 * 4;
      h += v.x * Wl[k * 64 + lane] + v.y * Wl[(k + 1) * 64 + lane]
         + v.z * Wl[(k + 2) * 64 + lane] + v.w * Wl[(k + 3) * 64 + lane];
    }
    float p1 = h * a1l, p2 = h * a2l;
#pragma unroll
    for (int off = 32; off > 0; off >>= 1) { p1 += __shfl_xor(p1, off); p2 += __shfl_xor(p2, off); }
    hsm[jn][lane] = h;
    if (lane == 0) {
      const float s1 = p1, s2 = p2;
      const float e1 = expf(s2 - C1), e2 = expf(ALPHA * s2);
      e1sm[jn] = e1; e2sm[jn] = e2;
      e1h[j] = f2h(e1);
      thh[j] = f2h(expf(-s1 - C1));            // pos branch iff e1h[j] > thh[i] (u16-monotone)
      f1g[j] = expf(s1 + C1);
      f2g[j] = expf(ALPHA * s1);
    }
  }
  __syncthreads();
  // phase B: this block covers half a k32 slab: lanes [hi, hi+32) of every n-chunk
  const int k32 = k16 >> 1, hi = (k16 & 1) * 32;
  for (int cc = tid; cc < 320; cc += 256) {
    const int n = cc >> 5, l32 = cc & 31;
    const int r = n * 16 + (l32 & 15);
    const int jb = (l32 >> 4) * 8;             // local node base for this lane's 8 elements
    u32 wpk[4];
#pragma unroll
    for (int p = 0; p < 4; ++p) {
      u16 hh[2];
#pragma unroll
      for (int q2 = 0; q2 < 2; ++q2) {
        const int jj = jb + p * 2 + q2;
        float v;
        if (r < 64)        v = e1sm[jj] * hsm[jj][r];
        else if (r == 64)  v = e1sm[jj];
        else if (r < 80)   v = 0.f;
        else if (r < 144)  v = e2sm[jj] * hsm[jj][r - 80];
        else if (r == 144) v = e2sm[jj];
        else               v = 0.f;
        hh[q2] = f2h(v);
      }
      wpk[p] = (u32)hh[0] | ((u32)hh[1] << 16);
    }
    ((uint4*)Btf)[(size_t)(k32 * 10 + n) * 64 + hi + l32] = make_uint4(wpk[0], wpk[1], wpk[2], wpk[3]);
  }
}

// ---------------- K_PACK: adj -> branch-resolved bit masks (R5-proven) -------------------
// P1 bit j of row i = adj[i][j]!=0 && e1h[j] > thh[i];  P2 = adj && !up.  1 block per row.
__global__ __launch_bounds__(256) void k_pack(
    const int* __restrict__ adj, const u16* __restrict__ e1h, const u16* __restrict__ thh,
    unsigned char* __restrict__ P1, unsigned char* __restrict__ P2)
{
  const int i = blockIdx.x, tid = threadIdx.x;
  const u16 th = thh[i];
  const int* arow = adj + (size_t)i * NN;
  unsigned char* p1r = P1 + (size_t)i * (NN / 8);
  unsigned char* p2r = P2 + (size_t)i * (NN / 8);
#pragma unroll
  for (int it = 0; it < NN / 2048; ++it) {
    const int cb = it * 2048 + tid * 8;
    intx4 a0 = *reinterpret_cast<const intx4*>(arow + cb);
    intx4 a1 = *reinterpret_cast<const intx4*>(arow + cb + 4);
    uint4 ev = *reinterpret_cast<const uint4*>(e1h + cb);
    const int av[8] = {a0.x, a0.y, a0.z, a0.w, a1.x, a1.y, a1.z, a1.w};
    const u32 ew[4] = {ev.x, ev.y, ev.z, ev.w};
    u32 b1 = 0, b2 = 0;
#pragma unroll
    for (int e = 0; e < 8; ++e) {
      const u16 eh = (u16)(ew[e >> 1] >> ((e & 1) * 16));
      const bool bit = av[e] != 0;
      const bool up = eh > th;                 // positive fp16 compares as u16
      b1 |= (u32)(bit && up) << e;
      b2 |= (u32)(bit && !up) << e;
    }
    p1r[it * 256 + tid] = (unsigned char)b1;
    p2r[it * 256 + tid] = (unsigned char)b2;
  }
}

// ---------------- K2: LDS-staged bit-masked dual GEMM --------------------------------------
// 768 blocks = 96 mpos x 8 ksplit (bid&7=ks -> XCD k-affinity). Block: M=128, waves split M
// (32 rows each), share the 20-KB k64 B-slab via double-buffered LDS. One barrier/iter.
__global__ __launch_bounds__(256, 3) void k2_main(
    const u64* __restrict__ P1, const u64* __restrict__ P2,
    const u16* __restrict__ Btf, float* __restrict__ part)
{
  __shared__ u16 sB[2][10240];                 // 2 x 20 KB k64 slabs
  const int tid = threadIdx.x;
  const int wave = tid >> 6, lane = tid & 63;
  const int quad = lane >> 4, lr = lane & 15;
  const int mpos = (int)blockIdx.x >> 3;
  const int ks = (int)blockIdx.x & 7;
  const int mbase = mpos * 128 + wave * 32;
  const int k0 = ks * KRANGE;

  const u64* p1r[2] = {P1 + (size_t)(mbase + lr) * 192, P1 + (size_t)(mbase + 16 + lr) * 192};
  const u64* p2r[2] = {P2 + (size_t)(mbase + lr) * 192, P2 + (size_t)(mbase + 16 + lr) * 192};

  floatx4 acc[2][10];
#pragma unroll
  for (int t = 0; t < 2; ++t)
#pragma unroll
    for (int n = 0; n < 10; ++n) acc[t][n] = (floatx4){0.f, 0.f, 0.f, 0.f};

  const uint4* gB = (const uint4*)Btf;
  {                                            // pre-stage slab 0
    const uint4* src = gB + (size_t)(k0 >> 5) * 640;
#pragma unroll
    for (int i = 0; i < 5; ++i) ((uint4*)sB[0])[tid + i * 256] = src[tid + i * 256];
  }

  u64 P1w[2], P2w[2];
  for (int it = 0; it < ITERS; ++it) {
    __syncthreads();                           // sB[it&1] ready; sB[it&1] reads of prev iter drained
    const int cur = it & 1;
    uint4 stg[5];
    const bool more = (it + 1 < ITERS);
    if (more) {                                // issue next-slab loads; kept in flight over compute
      const uint4* src = gB + (size_t)((k0 + (it + 1) * 64) >> 5) * 640;
#pragma unroll
      for (int i = 0; i < 5; ++i) stg[i] = src[tid + i * 256];
    }
    if ((it & 3) == 0) {                       // batched P-words: 4 iters per load, quad=kword
      const int kw0 = (k0 >> 6) + it;
#pragma unroll
      for (int t = 0; t < 2; ++t) {
        P1w[t] = p1r[t][kw0 + quad];
        P2w[t] = p2r[t][kw0 + quad];
      }
    }
    const int j = it & 3;
    u64 b1[2], b2[2];
#pragma unroll
    for (int t = 0; t < 2; ++t) {              // redistribute: row lr's word for kword j
      b1[t] = __shfl(P1w[t], (j << 4) | lr);
      b2[t] = __shfl(P2w[t], (j << 4) | lr);
    }
#pragma unroll
    for (int h = 0; h < 2; ++h) {
      const u32 sh = (u32)(h * 32 + quad * 8);
      union { half8 v; u16 s[8]; } A1[2], A2[2];
      const u32 m1a = (u32)(b1[0] >> sh) & 0xFFu, m2a = (u32)(b2[0] >> sh) & 0xFFu;
      const u32 m1b = (u32)(b1[1] >> sh) & 0xFFu, m2b = (u32)(b2[1] >> sh) & 0xFFu;
#pragma unroll
      for (int e = 0; e < 8; ++e) {
        A1[0].s[e] = ((m1a >> e) & 1u) ? (u16)0x3C00 : (u16)0;
        A2[0].s[e] = ((m2a >> e) & 1u) ? (u16)0x3C00 : (u16)0;
        A1[1].s[e] = ((m1b >> e) & 1u) ? (u16)0x3C00 : (u16)0;
        A2[1].s[e] = ((m2b >> e) & 1u) ? (u16)0x3C00 : (u16)0;
      }
      const u16* bp = &sB[cur][h * 5120];
#pragma unroll
      for (int n = 0; n < 10; ++n) {
        half8 Bv = *(const half8*)(bp + (n * 64 + lane) * 8);
        acc[0][n] = __builtin_amdgcn_mfma_f32_16x16x32_f16(n < 5 ? A1[0].v : A2[0].v, Bv,
                                                           acc[0][n], 0, 0, 0);
        acc[1][n] = __builtin_amdgcn_mfma_f32_16x16x32_f16(n < 5 ? A1[1].v : A2[1].v, Bv,
                                                           acc[1][n], 0, 0, 0);
      }
    }
    if (more) {                                // commit staged slab (cur^1); barrier protects
      const int nb = cur ^ 1;
#pragma unroll
      for (int i = 0; i < 5; ++i) ((uint4*)sB[nb])[tid + i * 256] = stg[i];
    }
  }

  // partial store. C/D: col=lane&15, row=quad*4+reg; tile t -> local rows wave*32+t*16+..
  const int ks96 = ks * 96 + mpos;
#pragma unroll
  for (int t = 0; t < 2; ++t) {
    float* pp = part + ((size_t)ks96 * 128 + wave * 32 + t * 16 + quad * 4) * 132;
#pragma unroll
    for (int r = 0; r < 4; ++r) {
#pragma unroll
      for (int n = 0; n < 4; ++n)
        pp[r * 132 + n * 16 + lr] = acc[t][n][r];
#pragma unroll
      for (int n = 5; n < 9; ++n)
        pp[r * 132 + 64 + (n - 5) * 16 + lr] = acc[t][n][r];
      if (lr == 0) {
        pp[r * 132 + 128] = acc[t][4][r];      // den+ (group 4, col 0)
        pp[r * 132 + 129] = acc[t][9][r];      // den- (group 9, col 0)
      }
    }
  }
}

// ---------------- K3: reduce 8 k-split partials, scale, divide, ELU ----------------------
__global__ __launch_bounds__(256) void k3_final(
    const float* __restrict__ part, const float* __restrict__ f1g,
    const float* __restrict__ f2g, float* __restrict__ out)
{
  const int gid = blockIdx.x * 256 + threadIdx.x;
  const int row = gid >> 6, col = gid & 63;
  const int mpos = row >> 7, r = row & 127;
  float n1 = 0.f, n2 = 0.f, d1 = 0.f, d2 = 0.f;
#pragma unroll
  for (int ks = 0; ks < KSP; ++ks) {
    const float* p = part + ((size_t)(ks * 96 + mpos) * 128 + r) * 132;
    n1 += p[col]; n2 += p[64 + col]; d1 += p[128]; d2 += p[129];
  }
  const float f1 = f1g[row], f2 = f2g[row];
  const float num = f1 * n1 + f2 * n2;
  const float den = fmaxf(f1 * d1 + f2 * d2, 1e-30f);
  const float x = num / den;
  out[gid] = x > 0.f ? x : (expf(x) - 1.f);
}

extern "C" void kernel_launch(void* const* d_in, const int* in_sizes, int n_in,
                              void* d_out, int out_size, void* d_ws, size_t ws_size,
                              hipStream_t stream) {
  const float* inp = (const float*)d_in[0];
  const int* adj = (const int*)d_in[1];
  const float* W = (const float*)d_in[2];
  const float* a = (const float*)d_in[3];

  // ws: Btf 3,932,160 | P1 18,874,368 | P2 18,874,368 | part 51,904,512 | scalars
  char* ws = (char*)d_ws;
  u16* Btf = (u16*)ws;
  unsigned char* P1 = (unsigned char*)(ws + 3932160);
  unsigned char* P2 = P1 + 18874368;
  float* part = (float*)(ws + 3932160 + 2 * 18874368);
  char* tail = ws + 3932160 + 2 * 18874368 + 51904512;
  u16* e1h = (u16*)tail;
  u16* thh = e1h + NN;
  float* f1g = (float*)(thh + NN);
  float* f2g = f1g + NN;

  k1_prep<<<768, 256, 0, stream>>>(inp, W, a, e1h, thh, f1g, f2g, Btf);
  k_pack<<<NN, 256, 0, stream>>>(adj, e1h, thh, P1, P2);
  k2_main<<<768, 256, 0, stream>>>((const u64*)P1, (const u64*)P2, Btf, part);
  k3_final<<<NN * OUTF / 256, 256, 0, stream>>>(part, f1g, f2g, (float*)d_out);
}

// Round 10
// 850.846 us; speedup vs baseline: 2.6723x; 1.0564x over previous
//
#include <hip/hip_runtime.h>

#define NN 12288
#define OUTF 64
#define ALPHA 0.2f
#define C1 6.0f
#define KSP 8
#define KRANGE (NN / KSP)    /* 1536 per block */
#define ITERS (KRANGE / 64)  /* 24 */

typedef unsigned short u16;
typedef unsigned int u32;
typedef unsigned long long u64;
typedef _Float16 half8 __attribute__((ext_vector_type(8)));
typedef float floatx4 __attribute__((ext_vector_type(4)));
typedef int intx4 __attribute__((ext_vector_type(4)));

union H16 { u16 u; _Float16 h; };
__device__ __forceinline__ u16 f2h(float f) { H16 c; c.h = (_Float16)f; return c.u; }

// async global->LDS DMA, 16 B per lane; lds dest = wave-uniform base + lane*16
__device__ __forceinline__ void g2l16(const void* g, void* l) {
  __builtin_amdgcn_global_load_lds(
      (const __attribute__((address_space(1))) void*)g,
      (__attribute__((address_space(3))) void*)l, 16, 0, 0);
}

// ---------------- K1: h = X@W, per-node scalars, Btf in MFMA-fragment order --------------
// Btf chunk (k32, n): 64 lanes x 16 B contiguous; lane element j' = B_row(n*16+lane%16),
// source node k32*32 + (lane/16)*8 + j'.  B_row r: r<64: e1*h[r]; r==64: e1; 65..79: 0;
// 80..143: e2*h[r-80]; r==144: e2; 145..159: 0.   e1=exp(s2-C1), e2=exp(a*s2).
__global__ __launch_bounds__(256) void k1_prep(
    const float* __restrict__ inp, const float* __restrict__ W, const float* __restrict__ a,
    u16* __restrict__ e1h, u16* __restrict__ thh,
    float* __restrict__ f1g, float* __restrict__ f2g, u16* __restrict__ Btf)
{
  __shared__ float Wl[128 * 64];
  __shared__ float hsm[16][66];
  __shared__ float e1sm[16], e2sm[16];
  const int tid = threadIdx.x;
  for (int t = tid; t < 128 * 64 / 4; t += 256)
    ((float4*)Wl)[t] = ((const float4*)W)[t];
  const int wave = tid >> 6, lane = tid & 63;
  const int k16 = blockIdx.x;                  // 16-node group
  const float a1l = a[lane], a2l = a[OUTF + lane];
  __syncthreads();
  for (int jl = 0; jl < 4; ++jl) {
    const int jn = wave * 4 + jl;              // local node 0..15
    const int j = k16 * 16 + jn;
    const float4* xp = (const float4*)(inp + (size_t)j * 128);
    float h = 0.f;
#pragma unroll
    for (int c4 = 0; c4 < 32; ++c4) {
      float4 v = xp[c4];
      const int k = c4 * 4;
      h += v.x * Wl[k * 64 + lane] + v.y * Wl[(k + 1) * 64 + lane]
         + v.z * Wl[(k + 2) * 64 + lane] + v.w * Wl[(k + 3) * 64 + lane];
    }
    float p1 = h * a1l, p2 = h * a2l;
#pragma unroll
    for (int off = 32; off > 0; off >>= 1) { p1 += __shfl_xor(p1, off); p2 += __shfl_xor(p2, off); }
    hsm[jn][lane] = h;
    if (lane == 0) {
      const float s1 = p1, s2 = p2;
      const float e1 = expf(s2 - C1), e2 = expf(ALPHA * s2);
      e1sm[jn] = e1; e2sm[jn] = e2;
      e1h[j] = f2h(e1);
      thh[j] = f2h(expf(-s1 - C1));            // pos branch iff e1h[j] > thh[i] (u16-monotone)
      f1g[j] = expf(s1 + C1);
      f2g[j] = expf(ALPHA * s1);
    }
  }
  __syncthreads();
  // phase B: this block covers half a k32 slab: lanes [hi, hi+32) of every n-chunk
  const int k32 = k16 >> 1, hi = (k16 & 1) * 32;
  for (int cc = tid; cc < 320; cc += 256) {
    const int n = cc >> 5, l32 = cc & 31;
    const int r = n * 16 + (l32 & 15);
    const int jb = (l32 >> 4) * 8;             // local node base for this lane's 8 elements
    u32 wpk[4];
#pragma unroll
    for (int p = 0; p < 4; ++p) {
      u16 hh[2];
#pragma unroll
      for (int q2 = 0; q2 < 2; ++q2) {
        const int jj = jb + p * 2 + q2;
        float v;
        if (r < 64)        v = e1sm[jj] * hsm[jj][r];
        else if (r == 64)  v = e1sm[jj];
        else if (r < 80)   v = 0.f;
        else if (r < 144)  v = e2sm[jj] * hsm[jj][r - 80];
        else if (r == 144) v = e2sm[jj];
        else               v = 0.f;
        hh[q2] = f2h(v);
      }
      wpk[p] = (u32)hh[0] | ((u32)hh[1] << 16);
    }
    ((uint4*)Btf)[(size_t)(k32 * 10 + n) * 64 + hi + l32] = make_uint4(wpk[0], wpk[1], wpk[2], wpk[3]);
  }
}

// ---------------- K2: FUSED adj-pack + LDS-staged bit-masked dual GEMM -------------------
// 768 blocks = 96 mpos x 8 ksplit (bid&7 = ks = XCD -> per-XCD 480 KB B-slab L2 affinity).
// Per k64 iter: DMA next 20-KB B-slab (global_load_lds), stream next 32-KB adj tile
// (nontemporal, each element read once grid-wide), pack branch-resolved mask bytes to a
// double-buffered 4-KB LDS mask buffer, MFMA on current slab. One barrier per iter.
__global__ __launch_bounds__(256, 3) void k2_main(
    const int* __restrict__ adj, const u16* __restrict__ e1h, const u16* __restrict__ thh,
    const u16* __restrict__ Btf, float* __restrict__ part)
{
  __shared__ u16 sB[2][10240];                 // 40 KB B slabs
  __shared__ u64 m1s[2][128];                  // 2 KB pos-branch masks
  __shared__ u64 m2s[2][128];                  // 2 KB neg-branch masks
  const int tid = threadIdx.x;
  const int wave = tid >> 6, lane = tid & 63;
  const int quad = lane >> 4, lr = lane & 15;
  const int mpos = (int)blockIdx.x >> 3;
  const int ks = (int)blockIdx.x & 7;
  const int mbase = mpos * 128;
  const int k0 = ks * KRANGE;

  // pack role: rows prow+32p (p=0..3), cols pcol*8..+8 of each k64 slab
  const int prow = tid >> 3, pcol = tid & 7;
  u16 thu[4];
#pragma unroll
  for (int p = 0; p < 4; ++p) thu[p] = thh[mbase + p * 32 + prow];
  const int* aB = adj + (size_t)(mbase + prow) * NN + k0 + pcol * 8;
  const u16* eB = e1h + k0 + pcol * 8;

  floatx4 acc[2][10];
#pragma unroll
  for (int t = 0; t < 2; ++t)
#pragma unroll
    for (int n = 0; n < 10; ++n) acc[t][n] = (floatx4){0.f, 0.f, 0.f, 0.f};

  intx4 aj[4][2];
  uint4 evv;

  // ---- prologue: DMA slab 0, pack masks for slab 0 into buffer 0 ----
  {
    const char* src = (const char*)(Btf + ((size_t)(k0 >> 5)) * 5120);
#pragma unroll
    for (int i = 0; i < 5; ++i)
      g2l16(src + i * 4096 + tid * 16, (char*)&sB[0][0] + i * 4096 + wave * 1024);
#pragma unroll
    for (int p = 0; p < 4; ++p) {
      aj[p][0] = __builtin_nontemporal_load((const intx4*)(aB + (size_t)p * 32 * NN));
      aj[p][1] = __builtin_nontemporal_load((const intx4*)(aB + (size_t)p * 32 * NN + 4));
    }
    evv = *(const uint4*)eB;
    u32 ev8[8] = {evv.x & 0xFFFFu, evv.x >> 16, evv.y & 0xFFFFu, evv.y >> 16,
                  evv.z & 0xFFFFu, evv.z >> 16, evv.w & 0xFFFFu, evv.w >> 16};
#pragma unroll
    for (int p = 0; p < 4; ++p) {
      const int av[8] = {aj[p][0].x, aj[p][0].y, aj[p][0].z, aj[p][0].w,
                         aj[p][1].x, aj[p][1].y, aj[p][1].z, aj[p][1].w};
      u32 b1 = 0, b2 = 0;
#pragma unroll
      for (int e = 0; e < 8; ++e) {
        const bool nbr = av[e] > 0;
        const bool up = ev8[e] > (u32)thu[p];
        b1 |= (u32)(nbr && up) << e;
        b2 |= (u32)(nbr && !up) << e;
      }
      ((unsigned char*)&m1s[0][p * 32 + prow])[pcol] = (unsigned char)b1;
      ((unsigned char*)&m2s[0][p * 32 + prow])[pcol] = (unsigned char)b2;
    }
  }

  for (int it = 0; it < ITERS; ++it) {
    __syncthreads();                           // slab/masks [cur] ready (drains DMA + LDS)
    const int cur = it & 1, nxt = cur ^ 1;
    const bool more = (it + 1 < ITERS);
    if (more) {                                // stage slab it+1: B via DMA, adj into regs
      const char* src = (const char*)(Btf + ((size_t)(k0 >> 5) + (it + 1) * 2) * 5120);
#pragma unroll
      for (int i = 0; i < 5; ++i)
        g2l16(src + i * 4096 + tid * 16, (char*)&sB[nxt][0] + i * 4096 + wave * 1024);
      const int koff = (it + 1) * 64;
#pragma unroll
      for (int p = 0; p < 4; ++p) {
        aj[p][0] = __builtin_nontemporal_load((const intx4*)(aB + (size_t)p * 32 * NN + koff));
        aj[p][1] = __builtin_nontemporal_load((const intx4*)(aB + (size_t)p * 32 * NN + koff + 4));
      }
      evv = *(const uint4*)(eB + koff);
    }

    // ---- MFMA on [cur] ----
    u64 w1[2], w2[2];
    w1[0] = m1s[cur][wave * 32 + lr];      w1[1] = m1s[cur][wave * 32 + 16 + lr];
    w2[0] = m2s[cur][wave * 32 + lr];      w2[1] = m2s[cur][wave * 32 + 16 + lr];
#pragma unroll
    for (int h = 0; h < 2; ++h) {
      const u32 sh = (u32)(h * 32 + quad * 8);
      union { half8 v; u16 s[8]; } A1[2], A2[2];
      const u32 m1a = (u32)(w1[0] >> sh) & 0xFFu, m2a = (u32)(w2[0] >> sh) & 0xFFu;
      const u32 m1b = (u32)(w1[1] >> sh) & 0xFFu, m2b = (u32)(w2[1] >> sh) & 0xFFu;
#pragma unroll
      for (int e = 0; e < 8; ++e) {
        A1[0].s[e] = ((m1a >> e) & 1u) ? (u16)0x3C00 : (u16)0;
        A2[0].s[e] = ((m2a >> e) & 1u) ? (u16)0x3C00 : (u16)0;
        A1[1].s[e] = ((m1b >> e) & 1u) ? (u16)0x3C00 : (u16)0;
        A2[1].s[e] = ((m2b >> e) & 1u) ? (u16)0x3C00 : (u16)0;
      }
      const u16* bp = &sB[cur][h * 5120];
#pragma unroll
      for (int n = 0; n < 10; ++n) {
        half8 Bv = *(const half8*)(bp + (n * 64 + lane) * 8);
        acc[0][n] = __builtin_amdgcn_mfma_f32_16x16x32_f16(n < 5 ? A1[0].v : A2[0].v, Bv,
                                                           acc[0][n], 0, 0, 0);
        acc[1][n] = __builtin_amdgcn_mfma_f32_16x16x32_f16(n < 5 ? A1[1].v : A2[1].v, Bv,
                                                           acc[1][n], 0, 0, 0);
      }
    }

    // ---- pack masks for slab it+1 into [nxt] ----
    if (more) {
      u32 ev8[8] = {evv.x & 0xFFFFu, evv.x >> 16, evv.y & 0xFFFFu, evv.y >> 16,
                    evv.z & 0xFFFFu, evv.z >> 16, evv.w & 0xFFFFu, evv.w >> 16};
#pragma unroll
      for (int p = 0; p < 4; ++p) {
        const int av[8] = {aj[p][0].x, aj[p][0].y, aj[p][0].z, aj[p][0].w,
                           aj[p][1].x, aj[p][1].y, aj[p][1].z, aj[p][1].w};
        u32 b1 = 0, b2 = 0;
#pragma unroll
        for (int e = 0; e < 8; ++e) {
          const bool nbr = av[e] > 0;
          const bool up = ev8[e] > (u32)thu[p];
          b1 |= (u32)(nbr && up) << e;
          b2 |= (u32)(nbr && !up) << e;
        }
        ((unsigned char*)&m1s[nxt][p * 32 + prow])[pcol] = (unsigned char)b1;
        ((unsigned char*)&m2s[nxt][p * 32 + prow])[pcol] = (unsigned char)b2;
      }
    }
  }

  // partial store. C/D: col=lane&15, row=quad*4+reg; tile t -> local rows wave*32+t*16+..
  const int ks96 = ks * 96 + mpos;
#pragma unroll
  for (int t = 0; t < 2; ++t) {
    float* pp = part + ((size_t)ks96 * 128 + wave * 32 + t * 16 + quad * 4) * 132;
#pragma unroll
    for (int r = 0; r < 4; ++r) {
#pragma unroll
      for (int n = 0; n < 4; ++n)
        pp[r * 132 + n * 16 + lr] = acc[t][n][r];
#pragma unroll
      for (int n = 5; n < 9; ++n)
        pp[r * 132 + 64 + (n - 5) * 16 + lr] = acc[t][n][r];
      if (lr == 0) {
        pp[r * 132 + 128] = acc[t][4][r];      // den+ (group 4, col 0)
        pp[r * 132 + 129] = acc[t][9][r];      // den- (group 9, col 0)
      }
    }
  }
}

// ---------------- K3: reduce 8 k-split partials, scale, divide, ELU ----------------------
__global__ __launch_bounds__(256) void k3_final(
    const float* __restrict__ part, const float* __restrict__ f1g,
    const float* __restrict__ f2g, float* __restrict__ out)
{
  const int gid = blockIdx.x * 256 + threadIdx.x;
  const int row = gid >> 6, col = gid & 63;
  const int mpos = row >> 7, r = row & 127;
  float n1 = 0.f, n2 = 0.f, d1 = 0.f, d2 = 0.f;
#pragma unroll
  for (int ks = 0; ks < KSP; ++ks) {
    const float* p = part + ((size_t)(ks * 96 + mpos) * 128 + r) * 132;
    n1 += p[col]; n2 += p[64 + col]; d1 += p[128]; d2 += p[129];
  }
  const float f1 = f1g[row], f2 = f2g[row];
  const float num = f1 * n1 + f2 * n2;
  const float den = fmaxf(f1 * d1 + f2 * d2, 1e-30f);
  const float x = num / den;
  out[gid] = x > 0.f ? x : (expf(x) - 1.f);
}

extern "C" void kernel_launch(void* const* d_in, const int* in_sizes, int n_in,
                              void* d_out, int out_size, void* d_ws, size_t ws_size,
                              hipStream_t stream) {
  const float* inp = (const float*)d_in[0];
  const int* adj = (const int*)d_in[1];
  const float* W = (const float*)d_in[2];
  const float* a = (const float*)d_in[3];

  // ws: Btf 3,932,160 | part 51,904,512 | e1h 24,576 | thh 24,576 | f1g 49,152 | f2g 49,152
  char* ws = (char*)d_ws;
  u16* Btf = (u16*)ws;
  float* part = (float*)(ws + 3932160);
  char* tail = ws + 3932160 + 51904512;
  u16* e1h = (u16*)tail;
  u16* thh = e1h + NN;
  float* f1g = (float*)(thh + NN);
  float* f2g = f1g + NN;

  k1_prep<<<768, 256, 0, stream>>>(inp, W, a, e1h, thh, f1g, f2g, Btf);
  k2_main<<<768, 256, 0, stream>>>(adj, e1h, thh, Btf, part);
  k3_final<<<NN * OUTF / 256, 256, 0, stream>>>(part, f1g, f2g, (float*)d_out);
}